// Round 9
// baseline (434.373 us; speedup 1.0000x reference)
//
#include <hip/hip_runtime.h>

#define N_NODES 50000
#define N_EDGES 800000
#define HEADS   8
#define HID     32
#define HC      256
#define NG      64
#define MAXD    64    // per-node LDS edge cache (incl self-loop); fallback if E>MAXD
#define SCAN_BLOCKS ((N_NODES + 255) / 256)   // 196

typedef unsigned short ushort_t;
typedef unsigned int   uint_t;

// ---- workspace layout (float offsets) ----
#define HB_OFF    0                // hb bf16 N*256 (25.6MB = 6.4M float slots)
#define Y_OFF     6400000          // y fp32 N*32 (= out@W1, pre-bias)
#define Z_OFF     8000000          // z fp32 N*32
#define AS_OFF    9600000          // a_s N*8 fp32
#define AD_OFF    10000000         // a_d N*8 fp32
#define ROW_OFF   10400000         // int row[N+1]
#define DEG_OFF   10450016         // int deg[N] (reused as fill cursor) [zero-init]
#define CSR_OFF   10500016         // int csr_src[N_EDGES]
#define GS_OFF    11300016         // int gstart[NG+1]
#define BSUM_OFF  11300088         // int bsum[SCAN_BLOCKS]
#define WS_END    11300284

__device__ __forceinline__ ushort_t f2bf(float f) {
    uint_t u = __float_as_uint(f);
    u = (u + 0x7FFFu + ((u >> 16) & 1u)) >> 16;   // RNE
    return (ushort_t)u;
}
__device__ __forceinline__ float bf_lo(uint_t u) { return __uint_as_float(u << 16); }
__device__ __forceinline__ float bf_hi(uint_t u) { return __uint_as_float(u & 0xFFFF0000u); }

__global__ __launch_bounds__(256) void k_zero(float* __restrict__ p, int n4) {
    int i = blockIdx.x * 256 + threadIdx.x;
    if (i < n4) ((float4*)p)[i] = make_float4(0.f, 0.f, 0.f, 0.f);
}

// hb = bf16(x @ W_gat), fused attention-coefficient epilogue.
// 16 nodes per block; thread t owns output column t.
__global__ __launch_bounds__(256) void k_gemm_h(const float* __restrict__ x,
                                                const float* __restrict__ Wg,
                                                const float* __restrict__ att_s,
                                                const float* __restrict__ att_d,
                                                ushort_t* __restrict__ hb,
                                                float* __restrict__ a_s,
                                                float* __restrict__ a_d) {
    __shared__ float xs[16 * 128];
    int t = threadIdx.x;
    int n0 = blockIdx.x * 16;
#pragma unroll
    for (int r = 0; r < 8; ++r) {
        int idx = t + r * 256;
        xs[idx] = x[n0 * 128 + idx];
    }
    __syncthreads();
    float acc[16];
#pragma unroll
    for (int i = 0; i < 16; ++i) acc[i] = 0.f;
    for (int k = 0; k < 128; k += 4) {
        float w0 = Wg[(k + 0) * 256 + t];
        float w1 = Wg[(k + 1) * 256 + t];
        float w2 = Wg[(k + 2) * 256 + t];
        float w3 = Wg[(k + 3) * 256 + t];
#pragma unroll
        for (int i = 0; i < 16; ++i) {
            float4 xv = *(const float4*)&xs[i * 128 + k];
            acc[i] = fmaf(xv.x, w0, acc[i]);
            acc[i] = fmaf(xv.y, w1, acc[i]);
            acc[i] = fmaf(xv.z, w2, acc[i]);
            acc[i] = fmaf(xv.w, w3, acc[i]);
        }
    }
#pragma unroll
    for (int i = 0; i < 16; ++i) hb[(n0 + i) * 256 + t] = f2bf(acc[i]);

    // attention epilogue: head = t>>5, channel-in-head = t&31; att flat idx = t
    float satt = att_s[t];
    float datt = att_d[t];
#pragma unroll
    for (int i = 0; i < 16; ++i) {
        float ps = acc[i] * satt;
        float pd = acc[i] * datt;
#pragma unroll
        for (int mask = 1; mask <= 16; mask <<= 1) {
            ps += __shfl_xor(ps, mask, 64);
            pd += __shfl_xor(pd, mask, 64);
        }
        if ((t & 31) == 0) {
            a_s[(n0 + i) * 8 + (t >> 5)] = ps;
            a_d[(n0 + i) * 8 + (t >> 5)] = pd;
        }
    }
}

// ---------- CSR build ----------
__global__ __launch_bounds__(256) void k_hist(const int* __restrict__ ei,
                                              int* __restrict__ deg) {
    int e = blockIdx.x * 256 + threadIdx.x;
    if (e < N_EDGES) atomicAdd(&deg[ei[N_EDGES + e]], 1);
}

__global__ __launch_bounds__(256) void k_scan1(const int* __restrict__ deg,
                                               int* __restrict__ row,
                                               int* __restrict__ bsum) {
    __shared__ int s[256];
    int t = threadIdx.x;
    int i = blockIdx.x * 256 + t;
    int v = (i < N_NODES) ? deg[i] : 0;
    s[t] = v;
    __syncthreads();
    for (int off = 1; off < 256; off <<= 1) {
        int u = (t >= off) ? s[t - off] : 0;
        __syncthreads();
        s[t] += u;
        __syncthreads();
    }
    if (i < N_NODES) row[i] = s[t] - v;       // exclusive, block-local
    if (t == 255) bsum[blockIdx.x] = s[255];
}

// phase 2: scan the 196 block sums; also compute graph bounds (independent work)
__global__ __launch_bounds__(256) void k_scan2(int* __restrict__ bsum,
                                               const int* __restrict__ batch,
                                               int* __restrict__ gs) {
    __shared__ int s[256];
    int t = threadIdx.x;
    int v = (t < SCAN_BLOCKS) ? bsum[t] : 0;
    s[t] = v;
    __syncthreads();
    for (int off = 1; off < 256; off <<= 1) {
        int u = (t >= off) ? s[t - off] : 0;
        __syncthreads();
        s[t] += u;
        __syncthreads();
    }
    if (t < SCAN_BLOCKS) bsum[t] = s[t] - v;  // exclusive
    if (t <= NG) {
        int lo = 0, hi = N_NODES;
        while (lo < hi) {
            int mid = (lo + hi) >> 1;
            if (batch[mid] < t) lo = mid + 1; else hi = mid;
        }
        gs[t] = lo;
    }
}

// phase 3: add block offsets; zero deg for reuse as scatter cursor
__global__ __launch_bounds__(256) void k_scan3(int* __restrict__ row,
                                               const int* __restrict__ bsum,
                                               int* __restrict__ deg) {
    int i = blockIdx.x * 256 + threadIdx.x;
    if (i < N_NODES) {
        row[i] += bsum[blockIdx.x];
        deg[i] = 0;
    }
    if (i == 0) row[N_NODES] = N_EDGES;       // sum of degrees is static
}

__global__ __launch_bounds__(256) void k_scatter(const int* __restrict__ ei,
                                                 const int* __restrict__ row,
                                                 int* __restrict__ fill,
                                                 int* __restrict__ csr) {
    int e = blockIdx.x * 256 + threadIdx.x;
    if (e >= N_EDGES) return;
    int d = ei[N_EDGES + e];
    int pos = row[d] + atomicAdd(&fill[d], 1);
    csr[pos] = ei[e];
}

// ---------- fused GAT: softmax + bf16 gather-aggregate + bias + relu + @W1 ----------
// One wave per node; all LDS state wave-private -> no __syncthreads().
// Phase-2 gather unrolled x8 with strength-reduced addressing (latency-bound loop).
__global__ __launch_bounds__(256) void k_gat(const int* __restrict__ row,
                                             const int* __restrict__ csr,
                                             const float* __restrict__ a_s,
                                             const float* __restrict__ a_d,
                                             const ushort_t* __restrict__ hb,
                                             const float* __restrict__ bg,
                                             const float* __restrict__ W1,
                                             float* __restrict__ y) {
    __shared__ int   s_src[4][MAXD];
    __shared__ float s_es[4][MAXD * 8];
    int g = threadIdx.x >> 6;
    int lane = threadIdx.x & 63;
    int n = blockIdx.x * 4 + g;            // N_NODES % 4 == 0
    int r0 = row[n], r1 = row[n + 1];
    int deg = r1 - r0;
    int E = deg + 1;                       // + implicit self loop
    bool cached = (E <= MAXD);
    if (cached) {
        for (int j = lane; j < deg; j += 64) s_src[g][j] = csr[r0 + j];
        if (lane == 0) s_src[g][deg] = n;  // self loop lives in the cache too
    }

    int hd = lane & 7, jl = lane >> 3;     // 8 edge-lanes x 8 heads
    const char* as_hd = (const char*)(a_s + hd);   // strength-reduced base
    float ad = a_d[n * 8 + hd];
    float pmax = -1e30f;
    for (int j = jl; j < E; j += 8) {
        int sj = cached ? s_src[g][j] : ((j < deg) ? csr[r0 + j] : n);
        float v = *(const float*)(as_hd + ((size_t)sj << 5)) + ad;
        v = v > 0.f ? v : 0.2f * v;
        if (cached) s_es[g][j * 8 + hd] = v;
        pmax = fmaxf(pmax, v);
    }
#pragma unroll
    for (int mask = 8; mask <= 32; mask <<= 1)
        pmax = fmaxf(pmax, __shfl_xor(pmax, mask, 64));
    float psum = 0.f;
    for (int j = jl; j < E; j += 8) {
        float v;
        if (cached) v = s_es[g][j * 8 + hd];
        else {
            int sj = (j < deg) ? csr[r0 + j] : n;
            v = *(const float*)(as_hd + ((size_t)sj << 5)) + ad;
            v = v > 0.f ? v : 0.2f * v;
        }
        psum += __expf(v - pmax);
    }
#pragma unroll
    for (int mask = 8; mask <= 32; mask <<= 1)
        psum += __shfl_xor(psum, mask, 64);
    float invden = 1.0f / psum;
    if (cached) {
        for (int j = jl; j < E; j += 8)
            s_es[g][j * 8 + hd] = __expf(s_es[g][j * 8 + hd] - pmax) * invden;
    }

    // phase 2: lane owns channels [lane*4, lane*4+4), head hd2 = lane>>3
    int hd2 = lane >> 3;
    const char* hlane = (const char*)(hb + lane * 4);  // per-lane base; +sj*512B
    float4 acc = make_float4(0.f, 0.f, 0.f, 0.f);
    if (cached) {
        const int* sp = &s_src[g][0];
        const float* ap = &s_es[g][hd2];
        int j = 0;
        for (; j + 8 <= E; j += 8) {
            int   sx[8];
            float al[8];
            uint2 uu[8];
#pragma unroll
            for (int i = 0; i < 8; ++i) {
                sx[i] = sp[j + i];
                al[i] = ap[(j + i) * 8];
            }
#pragma unroll
            for (int i = 0; i < 8; ++i)
                uu[i] = *(const uint2*)(hlane + ((size_t)sx[i] << 9));
#pragma unroll
            for (int i = 0; i < 8; ++i) {
                acc.x = fmaf(al[i], bf_lo(uu[i].x), acc.x);
                acc.y = fmaf(al[i], bf_hi(uu[i].x), acc.y);
                acc.z = fmaf(al[i], bf_lo(uu[i].y), acc.z);
                acc.w = fmaf(al[i], bf_hi(uu[i].y), acc.w);
            }
        }
        for (; j < E; ++j) {
            int sj = sp[j];
            float alpha = ap[j * 8];
            uint2 u = *(const uint2*)(hlane + ((size_t)sj << 9));
            acc.x = fmaf(alpha, bf_lo(u.x), acc.x);
            acc.y = fmaf(alpha, bf_hi(u.x), acc.y);
            acc.z = fmaf(alpha, bf_lo(u.y), acc.z);
            acc.w = fmaf(alpha, bf_hi(u.y), acc.w);
        }
    } else {
        float m2 = __shfl(pmax, hd2, 64);
        float inv2 = __shfl(invden, hd2, 64);
        float ad2 = a_d[n * 8 + hd2];
        for (int j = 0; j < E; ++j) {
            int sj = (j < deg) ? csr[r0 + j] : n;
            float v = a_s[sj * 8 + hd2] + ad2;
            v = v > 0.f ? v : 0.2f * v;
            float alpha = __expf(v - m2) * inv2;
            uint2 u = *(const uint2*)(hlane + ((size_t)sj << 9));
            acc.x = fmaf(alpha, bf_lo(u.x), acc.x);
            acc.y = fmaf(alpha, bf_hi(u.x), acc.y);
            acc.z = fmaf(alpha, bf_lo(u.y), acc.z);
            acc.w = fmaf(alpha, bf_hi(u.y), acc.w);
        }
    }
    float4 b = *(const float4*)(bg + lane * 4);
    acc.x = fmaxf(acc.x + b.x, 0.f);
    acc.y = fmaxf(acc.y + b.y, 0.f);
    acc.z = fmaxf(acc.z + b.z, 0.f);
    acc.w = fmaxf(acc.w + b.w, 0.f);

    // epilogue: y[n] = out_row @ W1 (256 -> 32). Reuse s_es[g] (wave-private).
    float* srow = &s_es[g][0];
    *(float4*)(srow + lane * 4) = acc;
    int col = lane & 31;
    int c0 = (lane >> 5) * 128;            // two lanes per col, half-row each
    float yv = 0.f;
    for (int c = c0; c < c0 + 128; c += 4) {
        float4 r = *(const float4*)(srow + c);
        yv = fmaf(r.x, W1[(c + 0) * 32 + col], yv);
        yv = fmaf(r.y, W1[(c + 1) * 32 + col], yv);
        yv = fmaf(r.z, W1[(c + 2) * 32 + col], yv);
        yv = fmaf(r.w, W1[(c + 3) * 32 + col], yv);
    }
    yv += __shfl_xor(yv, 32, 64);
    if (lane < 32) y[n * 32 + col] = yv;
}

// ---------- GIN on y (128 B rows) + MLP layer 2 ----------
// One wave per node, no barriers. Two half-waves take alternating edges
// (2 x 128B requests/step, unroll x4 -> 8 rows in flight), combine via shfl.
// z[n] = relu( relu(y[n] + sum_j y[src_j] + b1) @ W2 + b2 ).
__global__ __launch_bounds__(256) void k_gin_mlp(const int* __restrict__ row,
                                                 const int* __restrict__ csr,
                                                 const float* __restrict__ y,
                                                 const float* __restrict__ b1,
                                                 const float* __restrict__ W2,
                                                 const float* __restrict__ b2,
                                                 float* __restrict__ z) {
    __shared__ float s_z[4][32];
    int g = threadIdx.x >> 6;
    int lane = threadIdx.x & 63;
    int n = blockIdx.x * 4 + g;
    int col = lane & 31, half = lane >> 5;
    int r0 = row[n], r1 = row[n + 1];
    const char* ycol = (const char*)(y + col);     // +sj*128B
    float acc = (half == 0) ? (y[n * 32 + col] + b1[col]) : 0.f;
    int j = r0 + half;                              // this half-wave's edges: stride 2
    for (; j + 6 < r1; j += 8) {
        int s0 = csr[j], s1 = csr[j + 2], s2 = csr[j + 4], s3 = csr[j + 6];
        float v0 = *(const float*)(ycol + ((size_t)s0 << 7));
        float v1 = *(const float*)(ycol + ((size_t)s1 << 7));
        float v2 = *(const float*)(ycol + ((size_t)s2 << 7));
        float v3 = *(const float*)(ycol + ((size_t)s3 << 7));
        acc += (v0 + v1) + (v2 + v3);
    }
    for (; j < r1; j += 2)
        acc += *(const float*)(ycol + ((size_t)csr[j] << 7));
    acc += __shfl_xor(acc, 32, 64);
    float z1 = fmaxf(acc, 0.f);
    if (lane < 32) s_z[g][col] = z1;               // wave-private; no barrier
    // layer 2: lane covers col, k-half = half*16
    const float* zr = &s_z[g][0];
    int k0 = half * 16;
    float p = 0.f;
#pragma unroll
    for (int k = 0; k < 16; k += 4) {
        float4 zv = *(const float4*)(zr + k0 + k);
        p = fmaf(zv.x, W2[(k0 + k + 0) * 32 + col], p);
        p = fmaf(zv.y, W2[(k0 + k + 1) * 32 + col], p);
        p = fmaf(zv.z, W2[(k0 + k + 2) * 32 + col], p);
        p = fmaf(zv.w, W2[(k0 + k + 3) * 32 + col], p);
    }
    p += __shfl_xor(p, 32, 64);
    if (lane < 32) z[n * 32 + col] = fmaxf(p + b2[col], 0.f);
}

// one block per graph: mean-pool its contiguous z rows, then @Wf + bf
__global__ __launch_bounds__(128) void k_pool_final(const float* __restrict__ z,
                                                    const int* __restrict__ gs,
                                                    const float* __restrict__ Wf,
                                                    const float* __restrict__ bf,
                                                    float* __restrict__ outp) {
    __shared__ float part[4][32];
    __shared__ float sums[32];
    int g = blockIdx.x;
    int t = threadIdx.x;
    int col = t & 31, q = t >> 5;
    int r0 = gs[g], r1 = gs[g + 1];
    float s = 0.f;
    for (int r = r0 + q; r < r1; r += 4) s += z[r * 32 + col];
    part[q][col] = s;
    __syncthreads();
    if (t < 32) sums[t] = part[0][t] + part[1][t] + part[2][t] + part[3][t];
    __syncthreads();
    float inv = 1.0f / fmaxf((float)(r1 - r0), 1.0f);
    float acc = 0.f;
#pragma unroll
    for (int k = 0; k < 32; ++k)
        acc = fmaf(sums[k], Wf[k * 128 + t], acc);
    outp[g * 128 + t] = acc * inv + bf[t];
}

extern "C" void kernel_launch(void* const* d_in, const int* in_sizes, int n_in,
                              void* d_out, int out_size, void* d_ws, size_t ws_size,
                              hipStream_t stream) {
    const float* x     = (const float*)d_in[0];
    const int*   ei    = (const int*)d_in[1];
    const int*   batch = (const int*)d_in[2];
    const float* Wg    = (const float*)d_in[3];
    const float* att_s = (const float*)d_in[4];
    const float* att_d = (const float*)d_in[5];
    const float* bg    = (const float*)d_in[6];
    const float* W1    = (const float*)d_in[7];
    const float* b1    = (const float*)d_in[8];
    const float* W2    = (const float*)d_in[9];
    const float* b2    = (const float*)d_in[10];
    const float* Wf    = (const float*)d_in[11];
    const float* bf    = (const float*)d_in[12];
    float* ws = (float*)d_ws;

    ushort_t* hb  = (ushort_t*)(ws + HB_OFF);
    float* y      = ws + Y_OFF;
    float* z      = ws + Z_OFF;
    float* a_s    = ws + AS_OFF;
    float* a_d    = ws + AD_OFF;
    int*   row    = (int*)(ws + ROW_OFF);
    int*   deg    = (int*)(ws + DEG_OFF);
    int*   csr    = (int*)(ws + CSR_OFF);
    int*   gs     = (int*)(ws + GS_OFF);
    int*   bsum   = (int*)(ws + BSUM_OFF);

    // zero: deg (50000 ints)
    k_zero<<<(N_NODES / 4 + 255) / 256, 256, 0, stream>>>((float*)deg, N_NODES / 4);

    // CSR build (hierarchical scan; bounds merged into scan2)
    k_hist<<<(N_EDGES + 255) / 256, 256, 0, stream>>>(ei, deg);
    k_scan1<<<SCAN_BLOCKS, 256, 0, stream>>>(deg, row, bsum);
    k_scan2<<<1, 256, 0, stream>>>(bsum, batch, gs);
    k_scan3<<<SCAN_BLOCKS, 256, 0, stream>>>(row, bsum, deg);
    k_scatter<<<(N_EDGES + 255) / 256, 256, 0, stream>>>(ei, row, deg, csr);

    // GAT projection + attention coefficients (fused)
    k_gemm_h<<<N_NODES / 16, 256, 0, stream>>>(x, Wg, att_s, att_d, hb, a_s, a_d);
    // fused GAT: softmax + gather + bias/relu + @W1 -> y  (out never materialized)
    k_gat<<<N_NODES / 4, 256, 0, stream>>>(row, csr, a_s, a_d, hb, bg, W1, y);

    // GIN on projected y + MLP layer 2 -> z (one wave per node, no barriers)
    k_gin_mlp<<<N_NODES / 4, 256, 0, stream>>>(row, csr, y, b1, W2, b2, z);

    // per-graph mean pool + final linear
    k_pool_final<<<NG, 128, 0, stream>>>(z, gs, Wf, bf, (float*)d_out);
}